// Round 8
// baseline (625.203 us; speedup 1.0000x reference)
//
#include <hip/hip_runtime.h>
#include <math.h>

typedef __bf16 bf16;
typedef bf16 bf16x8 __attribute__((ext_vector_type(8)));
typedef bf16 bf16x4v __attribute__((ext_vector_type(4)));
typedef float f32x4 __attribute__((ext_vector_type(4)));

// Problem constants (B=4, S=2048, D=2048, H=16, dh=128)
#define BB 4
#define SS 2048
#define DD 2048
#define HH 16
#define DH 128

__device__ __forceinline__ void gload_lds16(const bf16* g, bf16* l) {
  __builtin_amdgcn_global_load_lds(
      (const __attribute__((address_space(1))) void*)g,
      (__attribute__((address_space(3))) void*)l, 16, 0, 0);
}

// ---------------------------------------------------------------- fused cast f32->bf16
// One launch: x (B*S*D) then wq,wk,wv,wo (D*D each) -> contiguous bf16 at out.
__global__ __launch_bounds__(256) void cast_all(const float* __restrict__ x,
                                                const float* __restrict__ w0,
                                                const float* __restrict__ w1,
                                                const float* __restrict__ w2,
                                                const float* __restrict__ w3,
                                                bf16* __restrict__ out) {
  const int i = blockIdx.x * blockDim.x + threadIdx.x;  // float4 index
  const int nxf = (BB * SS * DD) / 4;                   // 4M
  const int per = (DD * DD) / 4;                        // 1M = 1<<20
  const float* src;
  int off;
  if (i < nxf) {
    src = x; off = i;
  } else {
    const int j = i - nxf;
    const int sel = j >> 20;
    off = j & (per - 1);
    src = (sel == 0) ? w0 : (sel == 1) ? w1 : (sel == 2) ? w2 : w3;
  }
  const float4 v = ((const float4*)src)[off];
  bf16x4v o = {(bf16)v.x, (bf16)v.y, (bf16)v.z, (bf16)v.w};
  ((bf16x4v*)out)[i] = o;
}

// ---------------------------------------------------------------- GEMM 256x256, BK=64, counted-vmcnt pipeline
// (round-7 inner schedule, best measured ~687 TF for this shape family)
// MODE 3: fused QKV epilogue. N=6144 over [wq;wk;wv] (contiguous rows).
//   col<4096 -> RoPE + scatter (b,h,s,d) into Q/K; col>=4096 -> V^T scatter.
//   Branches are block-uniform (n0 is a multiple of 256; regions 2048-aligned).
// MODE 2: fp32 out row-major (final projection).
template <int MODE>
__global__ __launch_bounds__(512, 2) void gemm256(const bf16* __restrict__ A,
                                                  const bf16* __restrict__ Bw,
                                                  bf16* __restrict__ Cb,
                                                  float* __restrict__ Cf,
                                                  const int* __restrict__ pos,
                                                  int M, int N, int K) {
  __shared__ alignas(16) bf16 lA[2][2][256 * 32];  // [buf][khalf][row*32+k]
  __shared__ alignas(16) bf16 lB[2][2][256 * 32];

  const int tid = threadIdx.x;
  const int wave = tid >> 6, lane = tid & 63;
  const int quad = lane >> 4, l15 = lane & 15;
  const int wm = wave >> 2, wn = wave & 3;  // wave grid 2M x 4N

  // XCD-chunked remap (generic over grid): XCD x owns a contiguous m-slice
  // (A-panel L2-resident), all n-blocks. Requires total%8==0 (768, 256: ok).
  const int nbc = N >> 8;
  const int lin = blockIdx.y * gridDim.x + blockIdx.x;
  const int perx = (gridDim.x * gridDim.y) >> 3;
  const int swz = (lin & 7) * perx + (lin >> 3);
  const int m0 = (swz / nbc) * 256, n0 = (swz % nbc) * 256;

  // stage one 256x32 K-half (1024 16B chunks, 2/thread) into dst
  auto stageH = [&](bf16* dst, const bf16* src, int rbase, int u, int kh) {
#pragma unroll
    for (int j = 0; j < 2; ++j) {
      const int c = j * 512 + wave * 64 + lane;  // chunk id 0..1023
      const int row = c >> 2, p = c & 3;         // 4 chunks/row
      const int kc = p ^ (row & 3);              // inverse swizzle on source
      gload_lds16(src + (size_t)(rbase + row) * K + u * 64 + kh * 32 + kc * 8,
                  dst + (size_t)(j * 512 + wave * 64) * 8);
    }
  };

  auto rdA = [&](int buf, int kh, int mf) -> bf16x8 {
    const int row = wm * 128 + mf * 16 + l15;
    return *(const bf16x8*)(&lA[buf][kh][0] + row * 32 + ((quad ^ (row & 3)) * 8));
  };
  auto rdB = [&](int buf, int kh, int nf) -> bf16x8 {
    const int row = wn * 64 + nf * 16 + l15;
    return *(const bf16x8*)(&lB[buf][kh][0] + row * 32 + ((quad ^ (row & 3)) * 8));
  };

  f32x4 acc[8][4] = {};
  const int NT = K >> 6;  // 32

  // prologue: tile 0, all four K-halves (8 loads outstanding)
  stageH(&lA[0][0][0], A, m0, 0, 0);
  stageH(&lB[0][0][0], Bw, n0, 0, 0);
  stageH(&lA[0][1][0], A, m0, 0, 1);
  stageH(&lB[0][1][0], Bw, n0, 0, 1);

  bf16x8 af[8], bfr[2];
  for (int t = 0; t < NT; ++t) {
    const int buf = t & 1;
    const bool pre = (t + 1 < NT);

    // ---------------- P1: kh0 x nh0 ----------------
    asm volatile("s_waitcnt vmcnt(4)" ::: "memory");  // Ak0,Bk0(t) resident
    __builtin_amdgcn_s_barrier();
    __builtin_amdgcn_sched_barrier(0);
#pragma unroll
    for (int mf = 0; mf < 8; ++mf) af[mf] = rdA(buf, 0, mf);
    bfr[0] = rdB(buf, 0, 0);
    bfr[1] = rdB(buf, 0, 1);
    if (pre) stageH(&lA[buf ^ 1][0][0], A, m0, t + 1, 0);
    asm volatile("s_waitcnt lgkmcnt(0)" ::: "memory");
    __builtin_amdgcn_sched_barrier(0);
    __builtin_amdgcn_s_setprio(1);
#pragma unroll
    for (int mf = 0; mf < 8; ++mf)
#pragma unroll
      for (int nf = 0; nf < 2; ++nf)
        acc[mf][nf] = __builtin_amdgcn_mfma_f32_16x16x32_bf16(af[mf], bfr[nf], acc[mf][nf], 0, 0, 0);
    __builtin_amdgcn_s_setprio(0);
    __builtin_amdgcn_sched_barrier(0);

    // ---------------- P2: kh0 x nh1 (reuse af) ----------------
    bfr[0] = rdB(buf, 0, 2);
    bfr[1] = rdB(buf, 0, 3);
    if (pre) stageH(&lB[buf ^ 1][0][0], Bw, n0, t + 1, 0);
    asm volatile("s_waitcnt lgkmcnt(0)" ::: "memory");
    __builtin_amdgcn_sched_barrier(0);
    __builtin_amdgcn_s_setprio(1);
#pragma unroll
    for (int mf = 0; mf < 8; ++mf)
#pragma unroll
      for (int nf = 0; nf < 2; ++nf)
        acc[mf][nf + 2] = __builtin_amdgcn_mfma_f32_16x16x32_bf16(af[mf], bfr[nf], acc[mf][nf + 2], 0, 0, 0);
    __builtin_amdgcn_s_setprio(0);
    __builtin_amdgcn_sched_barrier(0);

    // ---------------- P3: kh1 x nh0 ----------------
    if (pre) asm volatile("s_waitcnt vmcnt(4)" ::: "memory");  // Ak1,Bk1(t)
    else     asm volatile("s_waitcnt vmcnt(0)" ::: "memory");  // last tile
    __builtin_amdgcn_s_barrier();
    __builtin_amdgcn_sched_barrier(0);
#pragma unroll
    for (int mf = 0; mf < 8; ++mf) af[mf] = rdA(buf, 1, mf);
    bfr[0] = rdB(buf, 1, 0);
    bfr[1] = rdB(buf, 1, 1);
    if (pre) stageH(&lA[buf ^ 1][1][0], A, m0, t + 1, 1);
    asm volatile("s_waitcnt lgkmcnt(0)" ::: "memory");
    __builtin_amdgcn_sched_barrier(0);
    __builtin_amdgcn_s_setprio(1);
#pragma unroll
    for (int mf = 0; mf < 8; ++mf)
#pragma unroll
      for (int nf = 0; nf < 2; ++nf)
        acc[mf][nf] = __builtin_amdgcn_mfma_f32_16x16x32_bf16(af[mf], bfr[nf], acc[mf][nf], 0, 0, 0);
    __builtin_amdgcn_s_setprio(0);
    __builtin_amdgcn_sched_barrier(0);

    // ---------------- P4: kh1 x nh1 (reuse af) ----------------
    bfr[0] = rdB(buf, 1, 2);
    bfr[1] = rdB(buf, 1, 3);
    if (pre) stageH(&lB[buf ^ 1][1][0], Bw, n0, t + 1, 1);
    asm volatile("s_waitcnt lgkmcnt(0)" ::: "memory");
    __builtin_amdgcn_sched_barrier(0);
    __builtin_amdgcn_s_setprio(1);
#pragma unroll
    for (int mf = 0; mf < 8; ++mf)
#pragma unroll
      for (int nf = 0; nf < 2; ++nf)
        acc[mf][nf + 2] = __builtin_amdgcn_mfma_f32_16x16x32_bf16(af[mf], bfr[nf], acc[mf][nf + 2], 0, 0, 0);
    __builtin_amdgcn_s_setprio(0);
    __builtin_amdgcn_sched_barrier(0);
  }

  // ---------------- epilogue ----------------
  const bool rope_blk = (MODE == 3) && (n0 < 2 * DD);
  float ps[8][4];
  if (rope_blk) {
#pragma unroll
    for (int mf = 0; mf < 8; ++mf)
#pragma unroll
      for (int r = 0; r < 4; ++r)
        ps[mf][r] = (float)pos[(m0 + wm * 128 + mf * 16 + quad * 4 + r) & (SS - 1)];
  }

#pragma unroll
  for (int nf = 0; nf < 4; ++nf) {
    const int col = n0 + wn * 64 + nf * 16 + l15;
    float invf = 0.f, sgn = 0.f;
    if (rope_blk) {
      const int d = col & (DH - 1);
      invf = exp2f((float)(d >> 1) * (-13.28771238f / 64.0f));  // 10000^(-2i/128)
      sgn = (d & 1) ? 1.0f : -1.0f;
    }
#pragma unroll
    for (int mf = 0; mf < 8; ++mf) {
#pragma unroll
      for (int r = 0; r < 4; ++r) {
        const int row = m0 + wm * 128 + mf * 16 + quad * 4 + r;  // C/D: row=quad*4+reg
        float v = acc[mf][nf][r];
        if (MODE == 3) {
          const int b = row >> 11, s = row & (SS - 1);
          const int cm = col & (DD - 1);
          const int h = cm >> 7, d = cm & (DH - 1);
          if (rope_blk) {
            // fused RoPE: pair partner is adjacent lane (col differs by 1)
            const float partner = __shfl_xor(v, 1);
            float sn, cn;
            __sincosf(ps[mf][r] * invf, &sn, &cn);
            v = fmaf(partner, sgn * sn, v * cn);
            const int mat = col >> 11;  // 0=Q, 1=K
            Cb[(size_t)mat * BB * SS * DD + ((((size_t)b * HH + h) * SS + s) << 7) + d] = (bf16)v;
          } else {
            // V^T scatter: (b,h,d,s)
            Cb[(size_t)2 * BB * SS * DD + (((size_t)b * HH + h) * DH + d) * SS + s] = (bf16)v;
          }
        } else {
          Cf[(size_t)row * N + col] = v;
        }
      }
    }
  }
}

// ---------------------------------------------------------------- flash attention v10 (v7 + V-latency hoist)
// QBLK=128 (4 waves x 32 q), KVBLK=64. K LDS-dbuf via global_load_lds;
// P per-wave LDS scratch; one barrier per tile; XCD-clustered head mapping;
// last two tiles masked. NEW: all 16 V b128 loads issued at iteration TOP,
// BEFORE the K-stage (so they are the OLDEST vmcnt entries and PV's wait
// does not force the stage to confirm). V's L2 latency (~2x400cy previously
// exposed serially in PV) now hides under QK MFMA + softmax (~1500cy).
__global__ __launch_bounds__(256, 2) void flash_attn(const bf16* __restrict__ Q,
                                                     const bf16* __restrict__ Kg,
                                                     const bf16* __restrict__ Vt,
                                                     bf16* __restrict__ O) {
  __shared__ alignas(16) bf16 lK[2][64 * 128];  // K tiles, swizzled 16B chunks
  __shared__ alignas(16) bf16 lP[4][32 * 64];   // per-wave P scratch [q][key]

  const int tid = threadIdx.x;
  const int wave = tid >> 6, lane = tid & 63;
  const int quad = lane >> 4, l15 = lane & 15;
  const int swz = l15 & 7;

  const int lin = blockIdx.y * gridDim.x + blockIdx.x;   // 0..1023
  const int bh = ((lin & 7) << 3) | ((lin >> 3) & 7);    // head id
  const int q0 = (15 - (lin >> 6)) * 128;                // heavy blocks first

  const bf16* Qh = Q + (size_t)bh * SS * DH;
  const bf16* Kh = Kg + (size_t)bh * SS * DH;
  const bf16* Vh = Vt + (size_t)bh * DH * SS;
  const int nkb = (q0 >> 6) + 2;
  const int qrow0 = q0 + wave * 32;

  bf16x8 qf[2][4];
#pragma unroll
  for (int qt = 0; qt < 2; ++qt)
#pragma unroll
    for (int t = 0; t < 4; ++t)
      qf[qt][t] = *(const bf16x8*)(Qh + (size_t)(qrow0 + qt * 16 + l15) * DH + t * 32 + quad * 8);

  bf16* lPw = &lP[wave][0];
  const float cs = 0.12751649736f;  // log2(e)/sqrt(128)
  const float MSTAT = 20.0f;        // static max (log2 domain)
  float lsum[2] = {0.f, 0.f};
  f32x4 oacc[2][8] = {};
  int cur = 0;

  auto stage = [&](int b, int kb) {
#pragma unroll
    for (int j = 0; j < 4; ++j) {
      const int c = tid + j * 256;
      const int kr = c >> 4;  // key row 0..63 (16 chunks/row)
      gload_lds16(Kh + (size_t)(kb * 64 + kr) * DH + (((c & 15) ^ (kr & 7)) * 8),
                  &lK[b][0] + (size_t)(wave * 64 + j * 256) * 8);
    }
  };

  auto kv_iter = [&](int kb, bool masked, bool stage_next) {
    int ktlim = 3;
    if (masked) {
      ktlim = (qrow0 + 31 - kb * 64) >> 4;
      if (ktlim < 0) return;  // only reachable on the final (non-staging) call
      if (ktlim > 3) ktlim = 3;
    }

    // ---- V loads FIRST: oldest vmcnt entries; latency hides under QK+softmax
    bf16x8 vf[8][2];
#pragma unroll
    for (int d8 = 0; d8 < 8; ++d8)
#pragma unroll
      for (int kc = 0; kc < 2; ++kc)
        vf[d8][kc] = *(const bf16x8*)(Vh + (size_t)(d8 * 16 + l15) * SS + kb * 64 +
                                      kc * 32 + quad * 8);

    // ---- next K tile stage (younger than vf: PV's vf-wait leaves it in flight)
    if (stage_next) stage(cur ^ 1, kb + 1);

    const bf16* kcur = &lK[cur][0];

    // ---- QK^T
    f32x4 sacc[2][4];
#pragma unroll
    for (int qt = 0; qt < 2; ++qt)
#pragma unroll
      for (int kt = 0; kt < 4; ++kt) sacc[qt][kt] = (f32x4){0.f, 0.f, 0.f, 0.f};
    __builtin_amdgcn_s_setprio(1);
#pragma unroll
    for (int kt = 0; kt < 4; ++kt) {
      if (kt <= ktlim) {
#pragma unroll
        for (int t = 0; t < 4; ++t) {
          const bf16x8 kfrag =
              *(const bf16x8*)(kcur + (kt * 16 + l15) * 128 + (((t * 4 + quad) ^ swz) * 8));
          sacc[0][kt] = __builtin_amdgcn_mfma_f32_16x16x32_bf16(kfrag, qf[0][t], sacc[0][kt], 0, 0, 0);
          sacc[1][kt] = __builtin_amdgcn_mfma_f32_16x16x32_bf16(kfrag, qf[1][t], sacc[1][kt], 0, 0, 0);
        }
      }
    }
    __builtin_amdgcn_s_setprio(0);

    // ---- softmax -> per-wave P scratch
#pragma unroll
    for (int kt = 0; kt < 4; ++kt) {
#pragma unroll
      for (int qt = 0; qt < 2; ++qt) {
        bf16x4v pk = {(bf16)0.f, (bf16)0.f, (bf16)0.f, (bf16)0.f};
        if (kt <= ktlim) {
          float ls = 0.f;
#pragma unroll
          for (int r = 0; r < 4; ++r) {
            float e = exp2f(fmaf(sacc[qt][kt][r], cs, -MSTAT));
            if (masked) {
              const int key = kb * 64 + kt * 16 + quad * 4 + r;
              if (key > qrow0 + qt * 16 + l15) e = 0.f;
            }
            ls += e;
            pk[r] = (bf16)e;
          }
          lsum[qt] += ls;
        }
        *(bf16x4v*)(lPw + (qt * 16 + l15) * 64 + (((kt * 2 + (quad >> 1)) ^ swz) * 8) +
                    (quad & 1) * 4) = pk;
      }
    }

    // ---- P readback as PV A-fragments (same wave; lgkmcnt orders w->r)
    bf16x8 pa[2][2];
#pragma unroll
    for (int qt = 0; qt < 2; ++qt)
#pragma unroll
      for (int kc = 0; kc < 2; ++kc)
        pa[qt][kc] = *(const bf16x8*)(lPw + (qt * 16 + l15) * 64 + (((kc * 4 + quad) ^ swz) * 8));

    // ---- PV with preloaded V
    __builtin_amdgcn_s_setprio(1);
#pragma unroll
    for (int d8 = 0; d8 < 8; ++d8)
#pragma unroll
      for (int kc = 0; kc < 2; ++kc) {
        oacc[0][d8] = __builtin_amdgcn_mfma_f32_16x16x32_bf16(pa[0][kc], vf[d8][kc], oacc[0][d8], 0, 0, 0);
        oacc[1][d8] = __builtin_amdgcn_mfma_f32_16x16x32_bf16(pa[1][kc], vf[d8][kc], oacc[1][d8], 0, 0, 0);
      }
    __builtin_amdgcn_s_setprio(0);
  };

  stage(0, 0);
  __syncthreads();

  for (int kb = 0; kb < nkb - 1; ++kb) {
    kv_iter(kb, kb + 2 >= nkb, true);
    __syncthreads();  // stage landed under compute; retires lK[cur]
    cur ^= 1;
  }
  kv_iter(nkb - 1, true, false);  // last (masked) tile; no trailing barrier

#pragma unroll
  for (int qt = 0; qt < 2; ++qt) {
    lsum[qt] += __shfl_xor(lsum[qt], 16);
    lsum[qt] += __shfl_xor(lsum[qt], 32);
  }

  const int b = bh >> 4, h = bh & 15;
#pragma unroll
  for (int qt = 0; qt < 2; ++qt) {
#pragma unroll
    for (int r = 0; r < 4; ++r) {
      const int qq = quad * 4 + r;
      const float il = 1.0f / __shfl(lsum[qt], qq);
      bf16* orow = O + ((size_t)b * SS + qrow0 + qt * 16 + qq) * DD + h * DH;
#pragma unroll
      for (int db = 0; db < 8; ++db) orow[db * 16 + l15] = (bf16)(oacc[qt][db][r] * il);
    }
  }
}

// ---------------------------------------------------------------- launch
extern "C" void kernel_launch(void* const* d_in, const int* in_sizes, int n_in,
                              void* d_out, int out_size, void* d_ws, size_t ws_size,
                              hipStream_t stream) {
  (void)in_sizes; (void)n_in; (void)out_size; (void)ws_size;
  const float* x = (const float*)d_in[0];
  const int* pos = (const int*)d_in[1];
  const float* wq = (const float*)d_in[2];
  const float* wk = (const float*)d_in[3];
  const float* wv = (const float*)d_in[4];
  const float* wo = (const float*)d_in[5];
  float* out = (float*)d_out;

  // workspace carve (bf16)
  bf16* xb  = (bf16*)d_ws;                 // B*S*D
  bf16* wqb = xb + (size_t)BB * SS * DD;   // D*D each (wq,wk,wv,wo contiguous)
  bf16* wob = wqb + (size_t)3 * DD * DD;
  bf16* Qb  = wob + (size_t)DD * DD;       // (B,H,S,128); K,V^T follow contiguously
  bf16* Kbf = Qb + (size_t)BB * SS * DD;
  bf16* Vtb = Kbf + (size_t)BB * SS * DD;  // (B,H,128,S)
  bf16* Ob  = Vtb + (size_t)BB * SS * DD;  // (B,S,2048)

  // one fused cast launch (x + all 4 weights)
  const int ntot4 = (BB * SS * DD + 4 * DD * DD) / 4;  // 8M float4
  cast_all<<<ntot4 / 256, 256, 0, stream>>>(x, wq, wk, wv, wo, xb);

  // fused QKV projection: N=6144 over contiguous [wq;wk;wv]
  gemm256<3><<<dim3(3 * DD / 256, (BB * SS) / 256), 512, 0, stream>>>(
      xb, wqb, Qb, nullptr, pos, BB * SS, 3 * DD, DD);

  flash_attn<<<dim3(SS / 128, BB * HH), 256, 0, stream>>>(Qb, Kbf, Vtb, Ob);

  gemm256<2><<<dim3(DD / 256, (BB * SS) / 256), 512, 0, stream>>>(
      Ob, wob, nullptr, out, nullptr, BB * SS, DD, DD);
}